// Round 14
// baseline (1162.256 us; speedup 1.0000x reference)
//
#include <hip/hip_runtime.h>
#include <math.h>

typedef unsigned short u16;
typedef __attribute__((ext_vector_type(8))) unsigned short u16x8;
typedef __attribute__((ext_vector_type(8))) __bf16 bf16x8;
typedef __attribute__((ext_vector_type(4))) float f32x4;

constexpr int Bc = 2, Sc = 2048, Mc = 1024, Ec = 512, Hc = 8, DH = 64, Fc = 2048, Vc = 8192, Lc = 6;
constexpr int Nc = Bc * Sc;    // 4096 decoder rows
constexpr int NMc = Bc * Mc;   // 2048 encoder rows

__device__ __forceinline__ u16 f2b(float f) {
  __bf16 h = (__bf16)f;
  return __builtin_bit_cast(u16, h);
}
__device__ __forceinline__ float b2f_lo(unsigned w) { return __builtin_bit_cast(float, w << 16); }
__device__ __forceinline__ float b2f_hi(unsigned w) { return __builtin_bit_cast(float, w & 0xFFFF0000u); }

__device__ __forceinline__ f32x4 mfma16(bf16x8 a, bf16x8 b, f32x4 c) {
  return __builtin_amdgcn_mfma_f32_16x16x32_bf16(a, b, c, 0, 0, 0);
}

// ---------------------------------------------------------------------------
// One-shot f32->bf16 conversion of all weights/embeddings (8 segments) PLUS
// the token embedding (segment 9: gather + positional add, 4 elems/thread).
// ---------------------------------------------------------------------------
constexpr int C0 = 1179648;
constexpr int C1 = C0 + 393216;
constexpr int C2 = C1 + 1179648;
constexpr int C3 = C2 + 393216;
constexpr int C4 = C3 + 1572864;
constexpr int C5 = C4 + 1572864;
constexpr int C6 = C5 + 1048576;
constexpr int C7 = C6 + 262144;        // cvt total 7602176 = 29696*256
constexpr int C8 = C7 + Nc * Ec / 4;   // + embed 524288 -> grid 31744

__global__ __launch_bounds__(256) void k_cvt_all(
    const float* __restrict__ s0, const float* __restrict__ s1,
    const float* __restrict__ s2, const float* __restrict__ s3,
    const float* __restrict__ s4, const float* __restrict__ s5,
    const float* __restrict__ s6, const float* __restrict__ s7,
    u16* __restrict__ d0, u16* __restrict__ d1, u16* __restrict__ d2,
    u16* __restrict__ d3, u16* __restrict__ d4, u16* __restrict__ d5,
    u16* __restrict__ d6, u16* __restrict__ d7,
    const int* __restrict__ seq, const float* __restrict__ pos,
    float* __restrict__ xs, u16* __restrict__ xb) {
  int i = blockIdx.x * 256 + threadIdx.x;
  if (i >= C7) {                        // embed segment
    int j = i - C7;
    int idx0 = j * 4;
    int row = idx0 >> 9, e = idx0 & 511;
    int s = row & (Sc - 1);
    float4 ev = *(const float4*)(s6 + (size_t)seq[row] * Ec + e);
    float4 pv = *(const float4*)(pos + (size_t)s * Ec + e);
    float4 v = make_float4(ev.x + pv.x, ev.y + pv.y, ev.z + pv.z, ev.w + pv.w);
    ((float4*)xs)[j] = v;
    unsigned lo = (unsigned)f2b(v.x) | ((unsigned)f2b(v.y) << 16);
    unsigned hi = (unsigned)f2b(v.z) | ((unsigned)f2b(v.w) << 16);
    ((uint2*)xb)[j] = make_uint2(lo, hi);
    return;
  }
  const float* s; u16* d; int off;
  if (i < C3) {
    if (i < C1) { if (i < C0) { s = s0; d = d0; off = i; }
                  else        { s = s1; d = d1; off = i - C0; } }
    else        { if (i < C2) { s = s2; d = d2; off = i - C1; }
                  else        { s = s3; d = d3; off = i - C2; } }
  } else {
    if (i < C5) { if (i < C4) { s = s4; d = d4; off = i - C3; }
                  else        { s = s5; d = d5; off = i - C4; } }
    else        { if (i < C6) { s = s6; d = d6; off = i - C5; }
                  else        { s = s7; d = d7; off = i - C6; } }
  }
  float4 v = ((const float4*)s)[off];
  unsigned lo = (unsigned)f2b(v.x) | ((unsigned)f2b(v.y) << 16);
  unsigned hi = (unsigned)f2b(v.z) | ((unsigned)f2b(v.w) << 16);
  ((uint2*)d)[off] = make_uint2(lo, hi);
}

// ---------------------------------------------------------------------------
// GEMM body: bf16 MFMA, swizzled LDS via global_load_lds (pre-swizzled src).
// Proven 2-buffer pipeline. lda/ldw = row strides; bias may be null.
// ---------------------------------------------------------------------------
template <int BM, int BN, int ACT>
__device__ __forceinline__ void gemm_body(const u16* __restrict__ A,
                                          const u16* __restrict__ W,
                                          const float* __restrict__ bias,
                                          float* __restrict__ C32,
                                          u16* __restrict__ Cb,
                                          int K, int lda, int ldw, int Mo,
                                          size_t row0, size_t col0) {
  constexpr int WM = BM / 2, WN = BN / 2, FM = WM / 16, FN = WN / 16;
  __shared__ __attribute__((aligned(16))) u16 As[2][BM * 64];
  __shared__ __attribute__((aligned(16))) u16 Bs[2][BN * 64];
  const int tid = threadIdx.x;
  const int w = tid >> 6, l = tid & 63, l15 = l & 15, l4 = l >> 4;
  const int lr = l >> 3, lc = l & 7;
  const int wr = (w >> 1) * WM, wc = (w & 1) * WN;
  const u16* Ab = A + row0 * lda;
  const u16* Wb = W + col0 * ldw;
  f32x4 acc[FM][FN] = {};

  auto stage = [&](int buf, int k0) {
#pragma unroll
    for (int i = 0; i < BM / 32; ++i) {
      int sw = lr ^ ((i * 4 + w) & 7);
      int row = i * 32 + w * 8 + lr;
      const u16* ga = Ab + (size_t)row * lda + k0 + ((lc ^ sw) & 7) * 8;
      __builtin_amdgcn_global_load_lds((const __attribute__((address_space(1))) void*)ga,
          (__attribute__((address_space(3))) void*)((char*)As[buf] + (i * 32 + w * 8) * 128), 16, 0, 0);
    }
#pragma unroll
    for (int i = 0; i < BN / 32; ++i) {
      int sw = lr ^ ((i * 4 + w) & 7);
      int row = i * 32 + w * 8 + lr;
      const u16* gw = Wb + (size_t)row * ldw + k0 + ((lc ^ sw) & 7) * 8;
      __builtin_amdgcn_global_load_lds((const __attribute__((address_space(1))) void*)gw,
          (__attribute__((address_space(3))) void*)((char*)Bs[buf] + (i * 32 + w * 8) * 128), 16, 0, 0);
    }
  };
  auto compute = [&](int buf) {
    const u16* AsC = As[buf];
    const u16* BsC = Bs[buf];
#pragma unroll
    for (int ks = 0; ks < 2; ++ks) {
      bf16x8 af[FM], bfr[FN];
#pragma unroll
      for (int m = 0; m < FM; ++m) {
        int ra = wr + m * 16 + l15;
        int sw = (l15 & 7) ^ ((wr / 8 + 2 * m + (l15 >> 3)) & 7);
        af[m] = *(const bf16x8*)&AsC[ra * 64 + ((ks * 32 + l4 * 8) ^ (sw * 8))];
      }
#pragma unroll
      for (int n = 0; n < FN; ++n) {
        int rb = wc + n * 16 + l15;
        int sw = (l15 & 7) ^ ((wc / 8 + 2 * n + (l15 >> 3)) & 7);
        bfr[n] = *(const bf16x8*)&BsC[rb * 64 + ((ks * 32 + l4 * 8) ^ (sw * 8))];
      }
#pragma unroll
      for (int m = 0; m < FM; ++m)
#pragma unroll
        for (int n = 0; n < FN; ++n)
          acc[m][n] = mfma16(af[m], bfr[n], acc[m][n]);
    }
  };

  const int nk = K / 64;
  stage(0, 0);
  int cur = 0;
  for (int kt = 0; kt < nk; ++kt) {
    __syncthreads();                 // drains vmcnt: stage(cur) landed
    if (kt + 1 < nk) stage(cur ^ 1, (kt + 1) * 64);   // overlap w/ compute
    compute(cur);
    cur ^= 1;
  }

#pragma unroll
  for (int n = 0; n < FN; ++n) {
    size_t col = col0 + wc + n * 16 + l15;
    float bv = bias ? bias[col] : 0.f;
#pragma unroll
    for (int m = 0; m < FM; ++m)
#pragma unroll
      for (int r = 0; r < 4; ++r) {
        size_t row = row0 + wr + m * 16 + l4 * 4 + r;
        float v = acc[m][n][r] + bv;
        if (ACT) v = 0.5f * v * (1.f + erff(v * 0.70710678118654752f));
        if (C32) C32[row * Mo + col] = v;
        if (Cb) Cb[row * Mo + col] = f2b(v);
      }
  }
}

// XS=1: bijective XCD column-chunk swizzle (requires gridDim.x % 8 == 0).
template <int BM, int BN, int ACT, int XS>
__global__ __launch_bounds__(256) void k_gemm_bf(const u16* __restrict__ A,
                                                 const u16* __restrict__ W,
                                                 const float* __restrict__ bias,
                                                 float* __restrict__ C32,
                                                 u16* __restrict__ Cb,
                                                 int K, int Mo) {
  int bx, by;
  if constexpr (XS) {
    int gx = gridDim.x;
    int bid = blockIdx.x + gx * blockIdx.y;
    int cw = gx >> 3;
    int xcd = bid & 7, j = bid >> 3;
    bx = xcd * cw + (j % cw);
    by = j / cw;
  } else {
    bx = blockIdx.x; by = blockIdx.y;
  }
  gemm_body<BM, BN, ACT>(A, W, bias, C32, Cb, K, K, K, Mo, (size_t)by * BM, (size_t)bx * BN);
}

// All-layer cross KV projection: grid 6*512; layer = bid>>9.
__global__ __launch_bounds__(256) void k_gemm_kv(const u16* __restrict__ encb,
                                                 const u16* __restrict__ wci,
                                                 const float* __restrict__ cib,
                                                 u16* __restrict__ kvb) {
  int bid = blockIdx.x;
  int lay = bid >> 9, r = bid & 511;
  int xcd = r & 7, j = r >> 3;
  int bx = xcd * 2 + (j & 1), by = j >> 1;       // 16 col-tiles x 32 row-tiles
  const u16* W = wci + (size_t)lay * 3 * Ec * Ec + (size_t)Ec * Ec;
  const float* b = cib + (size_t)lay * 3 * Ec + Ec;
  u16* out = kvb + (size_t)lay * NMc * 2 * Ec;
  gemm_body<64, 64, 0>(encb, W, b, nullptr, out, Ec, Ec, Ec, 2 * Ec,
                       (size_t)by * 64, (size_t)bx * 64);
}

// lin2 split-K: grid 1024; half = bid>>9 computes K in [half*1024, +1024).
__global__ __launch_bounds__(256) void k_gemm_lin2(const u16* __restrict__ hbf,
                                                   const u16* __restrict__ wl2_l,
                                                   const float* __restrict__ bias,
                                                   u16* __restrict__ t0,
                                                   u16* __restrict__ t1) {
  int bid = blockIdx.x;
  int half = bid >> 9, r = bid & 511;
  int xcd = r & 7, j = r >> 3;                   // 8 col-tiles x 64 row-tiles
  const u16* A = hbf + half * 1024;
  const u16* W = wl2_l + half * 1024;
  gemm_body<64, 64, 0>(A, W, half ? nullptr : bias, nullptr, half ? t1 : t0,
                       1024, Fc, Fc, Ec, (size_t)j * 64, (size_t)xcd * 64);
}

// ---------------------------------------------------------------------------
// Flash attention fd2 + swapped QK^T. ROUND 14: V prefetch distance 2 via
// parity register sets (tile j -> set j&1, slot j&1). writeV at iter i writes
// the set loaded at iter i-1 (full iteration of slack). K-landed guarantee
// restored by counted vmcnt before the barrier: vmcnt(2) when this iter's
// loadV is in flight (drains stageK, leaves loadV), else vmcnt(0).
// ---------------------------------------------------------------------------
__global__ __launch_bounds__(512, 4) void k_flash(const u16* __restrict__ Qp, int sq,
                                                  const u16* __restrict__ Kp,
                                                  const u16* __restrict__ Vp, int skv,
                                                  u16* __restrict__ Op, int so,
                                                  int Sq, int Sk, int causal) {
  __shared__ __attribute__((aligned(16))) u16 Kst[4][64 * 64];
  __shared__ __attribute__((aligned(16))) u16 Vt[4][64 * 64];
  __shared__ __attribute__((aligned(16))) u16 Pl[8][16 * 64];
  const int tid = threadIdx.x;
  const int w = tid >> 6, l = tid & 63, l15 = l & 15, l4 = l >> 4;
  const int wq = w & 3, ws = w >> 2;
  const int lr = l >> 3, lc = l & 7;
  const int t256 = tid & 255;
  const int kk2 = t256 >> 3, dblk = tid & 7;
  const int nqt = Sq / 64, nkt = Sk / 64;
  const int h = blockIdx.y, b = blockIdx.z;
  const int bx = blockIdx.x;
  const int qi = causal ? ((b & 1) ? bx : (nqt - 1 - bx)) : bx;
  const int qt0 = qi * 64;
  const int nt = causal ? (qi + 1) : nkt;
  const int NI = (nt + 1) >> 1;
  const u16* Qb = Qp + (size_t)b * Sq * sq + h * DH;
  const u16* Kb = Kp + (size_t)b * Sk * skv + h * DH;
  const u16* Vb = Vp + (size_t)b * Sk * skv + h * DH;
  const int qg = qt0 + wq * 16 + l15;

  bf16x8 qf[2];
  {
    const u16* qp0 = Qb + (size_t)qg * sq + l4 * 8;
    qf[0] = *(const bf16x8*)(qp0);
    qf[1] = *(const bf16x8*)(qp0 + 32);
  }

  f32x4 oacc[4] = {};
  float ls = 0.f, Mx = -3e38f;
  const float CSC = 0.18033688011112042f;
  const int swp = (l15 & 7) ^ (l15 >> 3);

  u16x8 vA0 = {}, vB0 = {}, vA1 = {}, vB1 = {};   // V parity register sets
  auto stageK = [&](int slot, int kt) {
#pragma unroll
    for (int i = 0; i < 2; ++i) {
      int sw = lr ^ ((i * 4 + wq) & 7);
      int row = i * 32 + wq * 8 + lr;
      const u16* src = Kb + (size_t)(kt + row) * skv + ((lc ^ sw) & 7) * 8;
      __builtin_amdgcn_global_load_lds((const __attribute__((address_space(1))) void*)src,
          (__attribute__((address_space(3))) void*)((char*)Kst[slot] + (i * 32 + wq * 8) * 128), 16, 0, 0);
    }
  };
  auto loadV = [&](int kt, u16x8& a, u16x8& bv) {
    const u16* vp0 = Vb + (size_t)(kt + 2 * kk2) * skv + dblk * 8;
    a = *(const u16x8*)vp0;
    bv = *(const u16x8*)(vp0 + skv);
  };
  auto writeV = [&](int slot, const u16x8& a, const u16x8& bv) {
    char* Vb_ = (char*)Vt[slot];
#pragma unroll
    for (int j = 0; j < 8; ++j) {
      int d = dblk * 8 + j;
      int sw = (j ^ dblk) & 7;
      unsigned pk = (unsigned)a[j] | ((unsigned)bv[j] << 16);
      *(unsigned*)(Vb_ + d * 128 + ((4 * kk2) ^ (sw << 4))) = pk;
    }
  };

  // prologue: tile j0 (t = ws) -> slot0/set0; preload tile j1 (t = ws+2) -> set1
  stageK(ws * 2, ws * 64);
  loadV(ws * 64, vA0, vB0);
  writeV(ws * 2, vA0, vB0);   // auto-vmcnt drains loadV(j0) AND stageK(j0) (older)
  if (2 + ws < nt) loadV((2 + ws) * 64, vA1, vB1);
  asm volatile("s_waitcnt lgkmcnt(0)" ::: "memory");
  __builtin_amdgcn_sched_barrier(0);
  __builtin_amdgcn_s_barrier();

  u16* Pw = Pl[w];
  for (int i = 0; i < NI; ++i) {
    const int t = 2 * i + ws;
    const int tK = t + 2;                 // tile i+1 (this slice)
    const int tV = t + 4;                 // tile i+2 (this slice)
    const bool haveK = tK < nt;
    const bool haveV = tV < nt;
    const int slotCur = ws * 2 + (i & 1);
    const int slotNxt = ws * 2 + ((i + 1) & 1);
    if (haveK) stageK(slotNxt, tK * 64);
    if (haveV) {                          // into set i&1 (its data hit LDS last iter)
      if (i & 1) loadV(tV * 64, vA1, vB1);
      else       loadV(tV * 64, vA0, vB0);
    }
    if (t < nt) {
      const u16* KstC = Kst[slotCur];
      const u16* VtC = Vt[slotCur];

      f32x4 sf[4] = {};
      __builtin_amdgcn_s_setprio(1);
#pragma unroll
      for (int n = 0; n < 4; ++n) {
        int rk = n * 16 + l15;
        int sw = (l15 & 7) ^ ((2 * n + (l15 >> 3)) & 7);
#pragma unroll
        for (int ks = 0; ks < 2; ++ks) {
          bf16x8 kf = *(const bf16x8*)&KstC[rk * 64 + ((ks * 32 + l4 * 8) ^ (sw * 8))];
          sf[n] = mfma16(kf, qf[ks], sf[n]);
        }
      }
      __builtin_amdgcn_s_setprio(0);

      if (causal && t == nt - 1) {
#pragma unroll
        for (int n = 0; n < 4; ++n)
#pragma unroll
          for (int r = 0; r < 4; ++r) {
            int kcol = t * 64 + n * 16 + l4 * 4 + r;
            if (kcol > qg) sf[n][r] = -3e38f;
          }
      }

      float tm = fmaxf(fmaxf(fmaxf(sf[0][0], sf[0][1]), fmaxf(sf[0][2], sf[0][3])),
                       fmaxf(fmaxf(sf[1][0], sf[1][1]), fmaxf(sf[1][2], sf[1][3])));
      tm = fmaxf(tm, fmaxf(fmaxf(fmaxf(sf[2][0], sf[2][1]), fmaxf(sf[2][2], sf[2][3])),
                           fmaxf(fmaxf(sf[3][0], sf[3][1]), fmaxf(sf[3][2], sf[3][3]))));
      tm = fmaxf(tm, __shfl_xor(tm, 16, 64));
      tm = fmaxf(tm, __shfl_xor(tm, 32, 64));
      float Mn = fmaxf(Mx, tm);
      float al = exp2f((Mx - Mn) * CSC);
      Mx = Mn;
      float mxc = Mx * CSC;

      float rs = 0.f;
#pragma unroll
      for (int n = 0; n < 4; ++n) {
        float p0 = exp2f(sf[n][0] * CSC - mxc);
        float p1 = exp2f(sf[n][1] * CSC - mxc);
        float p2 = exp2f(sf[n][2] * CSC - mxc);
        float p3 = exp2f(sf[n][3] * CSC - mxc);
        rs += (p0 + p1) + (p2 + p3);
        unsigned w0 = (unsigned)f2b(p0) | ((unsigned)f2b(p1) << 16);
        unsigned w1 = (unsigned)f2b(p2) | ((unsigned)f2b(p3) << 16);
        int bb = (n * 32 + l4 * 8) ^ (swp << 4);
        *(unsigned*)((char*)Pw + l15 * 128 + bb) = w0;
        *(unsigned*)((char*)Pw + l15 * 128 + bb + 4) = w1;
      }
      rs += __shfl_xor(rs, 16, 64);
      rs += __shfl_xor(rs, 32, 64);
      ls = ls * al + rs;

      if (__any(al < 1.f)) {
        float a0 = __shfl(al, l4 * 4 + 0, 64);
        float a1 = __shfl(al, l4 * 4 + 1, 64);
        float a2 = __shfl(al, l4 * 4 + 2, 64);
        float a3 = __shfl(al, l4 * 4 + 3, 64);
#pragma unroll
        for (int n2 = 0; n2 < 4; ++n2) {
          oacc[n2][0] *= a0; oacc[n2][1] *= a1;
          oacc[n2][2] *= a2; oacc[n2][3] *= a3;
        }
      }

      asm volatile("s_waitcnt lgkmcnt(0)" ::: "memory");
      __builtin_amdgcn_sched_barrier(0);

      __builtin_amdgcn_s_setprio(1);
#pragma unroll
      for (int ks = 0; ks < 2; ++ks) {
        bf16x8 pf = *(const bf16x8*)((char*)Pw + l15 * 128 + ((ks * 64 + l4 * 16) ^ (swp << 4)));
#pragma unroll
        for (int n2 = 0; n2 < 4; ++n2) {
          int rd = n2 * 16 + l15;
          int sw = (l15 & 7) ^ ((2 * n2 + (l15 >> 3)) & 7);
          bf16x8 vf = *(const bf16x8*)((char*)VtC + rd * 128 + ((ks * 64 + l4 * 16) ^ (sw << 4)));
          oacc[n2] = mfma16(pf, vf, oacc[n2]);
        }
      }
      __builtin_amdgcn_s_setprio(0);
    }

    // write V for tile i+1 from set (i+1)&1, loaded at iter i-1 (full slack)
    if (haveK) {
      if (i & 1) writeV(slotNxt, vA0, vB0);
      else       writeV(slotNxt, vA1, vB1);
    }
    if (haveV) asm volatile("s_waitcnt vmcnt(2)" ::: "memory");  // K landed, V in flight
    else       asm volatile("s_waitcnt vmcnt(0)" ::: "memory");  // drain all
    asm volatile("s_waitcnt lgkmcnt(0)" ::: "memory");
    __builtin_amdgcn_sched_barrier(0);
    __builtin_amdgcn_s_barrier();
  }

  __syncthreads();
  float* OB = (float*)&Kst[0][0];
  float* ML = (float*)&Vt[0][0];
  if (l4 == 0) {
    ML[ws * 64 + wq * 16 + l15] = Mx;
    ML[128 + ws * 64 + wq * 16 + l15] = ls;
  }
  if (ws == 1) {
#pragma unroll
    for (int n2 = 0; n2 < 4; ++n2)
#pragma unroll
      for (int r = 0; r < 4; ++r)
        OB[(wq * 16 + l4 * 4 + r) * 64 + n2 * 16 + l15] = oacc[n2][r];
  }
  __syncthreads();
  if (ws == 0) {
    u16* Ob = Op + (size_t)b * Sq * so + h * DH;
#pragma unroll
    for (int r = 0; r < 4; ++r) {
      int qs = wq * 16 + l4 * 4 + r;
      float mA = ML[qs], mB = ML[64 + qs];
      float lA = ML[128 + qs], lB = ML[192 + qs];
      float M = fmaxf(mA, mB);
      float aA = exp2f((mA - M) * CSC);
      float aB = exp2f((mB - M) * CSC);
      float inv = 1.f / (lA * aA + lB * aB);
      int qrow = qt0 + qs;
#pragma unroll
      for (int n2 = 0; n2 < 4; ++n2) {
        float o = (oacc[n2][r] * aA + OB[qs * 64 + n2 * 16 + l15] * aB) * inv;
        Ob[(size_t)qrow * so + n2 * 16 + l15] = f2b(o);
      }
    }
  }
}

// ---------------------------------------------------------------------------
// Residual + LayerNorm: one WAVE per row, 4 rows/block; thread l owns
// contiguous elements 8l..8l+7. bf16 residual inputs; rres2 optional.
// ---------------------------------------------------------------------------
__global__ __launch_bounds__(256) void k_res_ln(const float* __restrict__ xin,
                                                const u16* __restrict__ rres,
                                                const u16* __restrict__ rres2,
                                                const float* __restrict__ g,
                                                const float* __restrict__ bet,
                                                float* __restrict__ outf,
                                                u16* __restrict__ outb,
                                                int has_res) {
  const int tid = threadIdx.x, w = tid >> 6, l = tid & 63;
  const int row = blockIdx.x * 4 + w;
  const float4* xr = (const float4*)(xin + (size_t)row * Ec);
  float4 a = xr[2 * l], c = xr[2 * l + 1];
  if (has_res) {
    uint4 rv = ((const uint4*)(rres + (size_t)row * Ec))[l];
    a.x += b2f_lo(rv.x); a.y += b2f_hi(rv.x);
    a.z += b2f_lo(rv.y); a.w += b2f_hi(rv.y);
    c.x += b2f_lo(rv.z); c.y += b2f_hi(rv.z);
    c.z += b2f_lo(rv.w); c.w += b2f_hi(rv.w);
    if (rres2) {
      uint4 r2 = ((const uint4*)(rres2 + (size_t)row * Ec))[l];
      a.x += b2f_lo(r2.x); a.y += b2f_hi(r2.x);
      a.z += b2f_lo(r2.y); a.w += b2f_hi(r2.y);
      c.x += b2f_lo(r2.z); c.y += b2f_hi(r2.z);
      c.z += b2f_lo(r2.w); c.w += b2f_hi(r2.w);
    }
  }
  float s = (a.x + a.y) + (a.z + a.w) + (c.x + c.y) + (c.z + c.w);
#pragma unroll
  for (int o = 32; o; o >>= 1) s += __shfl_xor(s, o, 64);
  const float mean = s * (1.f / Ec);
  float d0 = a.x - mean, d1 = a.y - mean, d2 = a.z - mean, d3 = a.w - mean;
  float e0 = c.x - mean, e1 = c.y - mean, e2 = c.z - mean, e3 = c.w - mean;
  float vs = d0 * d0 + d1 * d1 + d2 * d2 + d3 * d3 +
             e0 * e0 + e1 * e1 + e2 * e2 + e3 * e3;
#pragma unroll
  for (int o = 32; o; o >>= 1) vs += __shfl_xor(vs, o, 64);
  const float inv = rsqrtf(vs * (1.f / Ec) + 1e-5f);
  float4 g0 = ((const float4*)g)[2 * l], g1 = ((const float4*)g)[2 * l + 1];
  float4 b0 = ((const float4*)bet)[2 * l], b1 = ((const float4*)bet)[2 * l + 1];
  float o0 = d0 * inv * g0.x + b0.x, o1 = d1 * inv * g0.y + b0.y;
  float o2 = d2 * inv * g0.z + b0.z, o3 = d3 * inv * g0.w + b0.w;
  float o4 = e0 * inv * g1.x + b1.x, o5 = e1 * inv * g1.y + b1.y;
  float o6 = e2 * inv * g1.z + b1.z, o7 = e3 * inv * g1.w + b1.w;
  if (outf) {
    float4* orow = (float4*)(outf + (size_t)row * Ec);
    orow[2 * l] = make_float4(o0, o1, o2, o3);
    orow[2 * l + 1] = make_float4(o4, o5, o6, o7);
  }
  if (outb) {
    uint4 pk;
    pk.x = (unsigned)f2b(o0) | ((unsigned)f2b(o1) << 16);
    pk.y = (unsigned)f2b(o2) | ((unsigned)f2b(o3) << 16);
    pk.z = (unsigned)f2b(o4) | ((unsigned)f2b(o5) << 16);
    pk.w = (unsigned)f2b(o6) | ((unsigned)f2b(o7) << 16);
    ((uint4*)(outb + (size_t)row * Ec))[l] = pk;
  }
}

// ---------------------------------------------------------------------------
extern "C" void kernel_launch(void* const* d_in, const int* in_sizes, int n_in,
                              void* d_out, int out_size, void* d_ws, size_t ws_size,
                              hipStream_t stream) {
  const float* encoded      = (const float*)d_in[0];
  const int*   seq          = (const int*)d_in[1];
  const float* input_embed  = (const float*)d_in[2];
  const float* pos_embed    = (const float*)d_in[3];
  const float* output_bias  = (const float*)d_in[4];
  const float* self_in_w    = (const float*)d_in[5];
  const float* self_in_b    = (const float*)d_in[6];
  const float* self_out_w   = (const float*)d_in[7];
  const float* self_out_b   = (const float*)d_in[8];
  const float* cross_in_w   = (const float*)d_in[9];
  const float* cross_in_b   = (const float*)d_in[10];
  const float* cross_out_w  = (const float*)d_in[11];
  const float* cross_out_b  = (const float*)d_in[12];
  const float* self_norm_g  = (const float*)d_in[13];
  const float* self_norm_b  = (const float*)d_in[14];
  const float* cross_norm_g = (const float*)d_in[15];
  const float* cross_norm_b = (const float*)d_in[16];
  const float* mlp_norm_g   = (const float*)d_in[17];
  const float* mlp_norm_b   = (const float*)d_in[18];
  const float* lin1_w       = (const float*)d_in[19];
  const float* lin1_b       = (const float*)d_in[20];
  const float* lin2_w       = (const float*)d_in[21];
  const float* lin2_b       = (const float*)d_in[22];
  const float* final_norm_g = (const float*)d_in[23];
  const float* final_norm_b = (const float*)d_in[24];

  char* oc = (char*)d_out;
  auto take = [&](size_t bytes) { char* p = oc; oc += bytes; return p; };
  u16* wsi  = (u16*)take((size_t)Lc * 3 * Ec * Ec * 2);
  u16* wso  = (u16*)take((size_t)Lc * Ec * Ec * 2);
  u16* wci  = (u16*)take((size_t)Lc * 3 * Ec * Ec * 2);
  u16* wco  = (u16*)take((size_t)Lc * Ec * Ec * 2);
  u16* wl1  = (u16*)take((size_t)Lc * Fc * Ec * 2);
  u16* wl2  = (u16*)take((size_t)Lc * Ec * Fc * 2);
  u16* encb = (u16*)take((size_t)NMc * Ec * 2);
  float* xs  = (float*)take((size_t)Nc * Ec * 4);
  float* ys  = (float*)take((size_t)Nc * Ec * 4);
  u16* tmpb  = (u16*)take((size_t)Nc * Ec * 2);
  u16* tmpb2 = (u16*)take((size_t)Nc * Ec * 2);
  u16* xbf  = (u16*)take((size_t)Nc * Ec * 2);
  u16* qkvb = (u16*)take((size_t)Nc * 3 * Ec * 2);
  u16* ctxb = (u16*)take((size_t)Nc * Ec * 2);
  u16* qxb  = (u16*)take((size_t)Nc * Ec * 2);
  u16* kvb  = (u16*)take((size_t)Lc * NMc * 2 * Ec * 2);
  u16* hbf  = qkvb;  // [Nc, Fc] aliases qkvb+ctxb (both dead at lin1)
  u16* xfb  = (u16*)d_ws;
  u16* embb = (u16*)((char*)d_ws + (size_t)Nc * Ec * 2);

  const dim3 blk(256);
  k_cvt_all<<<dim3(C8 / 256), blk, 0, stream>>>(
      self_in_w, self_out_w, cross_in_w, cross_out_w, lin1_w, lin2_w,
      input_embed, encoded, wsi, wso, wci, wco, wl1, wl2, embb, encb,
      seq, pos_embed, xs, xbf);

  k_gemm_kv<<<dim3(Lc * 512), blk, 0, stream>>>(encb, wci, cross_in_b, kvb);

  const dim3 gAttn(Sc / 64, Hc, Bc);
  const dim3 blkA(512);
  const dim3 gLN(Nc / 4);
  for (int l = 0; l < Lc; ++l) {
    const u16* wsi_l = wsi + (size_t)l * 3 * Ec * Ec;
    const u16* wci_l = wci + (size_t)l * 3 * Ec * Ec;
    u16* kvb_l = kvb + (size_t)l * NMc * 2 * Ec;
    // self attention
    k_gemm_bf<128, 64, 0, 1><<<dim3(3 * Ec / 64, Nc / 128), blk, 0, stream>>>(
        xbf, wsi_l, self_in_b + (size_t)l * 3 * Ec, nullptr, qkvb, Ec, 3 * Ec);
    k_flash<<<gAttn, blkA, 0, stream>>>(qkvb, 3 * Ec, qkvb + Ec, qkvb + 2 * Ec, 3 * Ec,
                                        ctxb, Ec, Sc, Sc, 1);
    k_gemm_bf<64, 64, 0, 1><<<dim3(Ec / 64, Nc / 64), blk, 0, stream>>>(
        ctxb, wso + (size_t)l * Ec * Ec, self_out_b + (size_t)l * Ec, nullptr, tmpb, Ec, Ec);
    k_res_ln<<<gLN, blk, 0, stream>>>(xs, tmpb, nullptr, self_norm_g + (size_t)l * Ec,
                                      self_norm_b + (size_t)l * Ec, ys, xbf, 1);
    // cross attention (KV precomputed)
    k_gemm_bf<64, 64, 0, 1><<<dim3(Ec / 64, Nc / 64), blk, 0, stream>>>(
        xbf, wci_l, cross_in_b + (size_t)l * 3 * Ec, nullptr, qxb, Ec, Ec);
    k_flash<<<gAttn, blkA, 0, stream>>>(qxb, Ec, kvb_l, kvb_l + Ec, 2 * Ec,
                                        ctxb, Ec, Sc, Mc, 0);
    k_gemm_bf<64, 64, 0, 1><<<dim3(Ec / 64, Nc / 64), blk, 0, stream>>>(
        ctxb, wco + (size_t)l * Ec * Ec, cross_out_b + (size_t)l * Ec, nullptr, tmpb, Ec, Ec);
    k_res_ln<<<gLN, blk, 0, stream>>>(ys, tmpb, nullptr, cross_norm_g + (size_t)l * Ec,
                                      cross_norm_b + (size_t)l * Ec, xs, xbf, 1);
    // MLP
    k_gemm_bf<128, 128, 1, 1><<<dim3(Fc / 128, Nc / 128), blk, 0, stream>>>(
        xbf, wl1 + (size_t)l * Fc * Ec, lin1_b + (size_t)l * Fc, nullptr, hbf, Ec, Fc);
    k_gemm_lin2<<<dim3(1024), blk, 0, stream>>>(
        hbf, wl2 + (size_t)l * Ec * Fc, lin2_b + (size_t)l * Ec, tmpb, tmpb2);
    k_res_ln<<<gLN, blk, 0, stream>>>(xs, tmpb, tmpb2, mlp_norm_g + (size_t)l * Ec,
                                      mlp_norm_b + (size_t)l * Ec, xs, xbf, 1);
  }

  k_res_ln<<<gLN, blk, 0, stream>>>(xs, nullptr, nullptr, final_norm_g, final_norm_b,
                                    nullptr, xfb, 0);
  k_gemm_bf<128, 128, 0, 1><<<dim3(Vc / 128, Nc / 128), blk, 0, stream>>>(
      xfb, embb, output_bias, (float*)d_out, nullptr, Ec, Vc);
}

// Round 15
// 1125.843 us; speedup vs baseline: 1.0323x; 1.0323x over previous
//
#include <hip/hip_runtime.h>
#include <math.h>

typedef unsigned short u16;
typedef __attribute__((ext_vector_type(8))) unsigned short u16x8;
typedef __attribute__((ext_vector_type(8))) __bf16 bf16x8;
typedef __attribute__((ext_vector_type(4))) float f32x4;

constexpr int Bc = 2, Sc = 2048, Mc = 1024, Ec = 512, Hc = 8, DH = 64, Fc = 2048, Vc = 8192, Lc = 6;
constexpr int Nc = Bc * Sc;    // 4096 decoder rows
constexpr int NMc = Bc * Mc;   // 2048 encoder rows

__device__ __forceinline__ u16 f2b(float f) {
  __bf16 h = (__bf16)f;
  return __builtin_bit_cast(u16, h);
}
__device__ __forceinline__ float b2f_lo(unsigned w) { return __builtin_bit_cast(float, w << 16); }
__device__ __forceinline__ float b2f_hi(unsigned w) { return __builtin_bit_cast(float, w & 0xFFFF0000u); }

__device__ __forceinline__ f32x4 mfma16(bf16x8 a, bf16x8 b, f32x4 c) {
  return __builtin_amdgcn_mfma_f32_16x16x32_bf16(a, b, c, 0, 0, 0);
}

// ---------------------------------------------------------------------------
// One-shot f32->bf16 conversion of all weights/embeddings (8 segments) PLUS
// the token embedding (segment 9: gather + positional add, 4 elems/thread).
// ---------------------------------------------------------------------------
constexpr int C0 = 1179648;
constexpr int C1 = C0 + 393216;
constexpr int C2 = C1 + 1179648;
constexpr int C3 = C2 + 393216;
constexpr int C4 = C3 + 1572864;
constexpr int C5 = C4 + 1572864;
constexpr int C6 = C5 + 1048576;
constexpr int C7 = C6 + 262144;        // cvt total 7602176 = 29696*256
constexpr int C8 = C7 + Nc * Ec / 4;   // + embed 524288 -> grid 31744

__global__ __launch_bounds__(256) void k_cvt_all(
    const float* __restrict__ s0, const float* __restrict__ s1,
    const float* __restrict__ s2, const float* __restrict__ s3,
    const float* __restrict__ s4, const float* __restrict__ s5,
    const float* __restrict__ s6, const float* __restrict__ s7,
    u16* __restrict__ d0, u16* __restrict__ d1, u16* __restrict__ d2,
    u16* __restrict__ d3, u16* __restrict__ d4, u16* __restrict__ d5,
    u16* __restrict__ d6, u16* __restrict__ d7,
    const int* __restrict__ seq, const float* __restrict__ pos,
    float* __restrict__ xs, u16* __restrict__ xb) {
  int i = blockIdx.x * 256 + threadIdx.x;
  if (i >= C7) {                        // embed segment
    int j = i - C7;
    int idx0 = j * 4;
    int row = idx0 >> 9, e = idx0 & 511;
    int s = row & (Sc - 1);
    float4 ev = *(const float4*)(s6 + (size_t)seq[row] * Ec + e);
    float4 pv = *(const float4*)(pos + (size_t)s * Ec + e);
    float4 v = make_float4(ev.x + pv.x, ev.y + pv.y, ev.z + pv.z, ev.w + pv.w);
    ((float4*)xs)[j] = v;
    unsigned lo = (unsigned)f2b(v.x) | ((unsigned)f2b(v.y) << 16);
    unsigned hi = (unsigned)f2b(v.z) | ((unsigned)f2b(v.w) << 16);
    ((uint2*)xb)[j] = make_uint2(lo, hi);
    return;
  }
  const float* s; u16* d; int off;
  if (i < C3) {
    if (i < C1) { if (i < C0) { s = s0; d = d0; off = i; }
                  else        { s = s1; d = d1; off = i - C0; } }
    else        { if (i < C2) { s = s2; d = d2; off = i - C1; }
                  else        { s = s3; d = d3; off = i - C2; } }
  } else {
    if (i < C5) { if (i < C4) { s = s4; d = d4; off = i - C3; }
                  else        { s = s5; d = d5; off = i - C4; } }
    else        { if (i < C6) { s = s6; d = d6; off = i - C5; }
                  else        { s = s7; d = d7; off = i - C6; } }
  }
  float4 v = ((const float4*)s)[off];
  unsigned lo = (unsigned)f2b(v.x) | ((unsigned)f2b(v.y) << 16);
  unsigned hi = (unsigned)f2b(v.z) | ((unsigned)f2b(v.w) << 16);
  ((uint2*)d)[off] = make_uint2(lo, hi);
}

// ---------------------------------------------------------------------------
// GEMM body: bf16 MFMA, swizzled LDS via global_load_lds (pre-swizzled src).
// Proven 2-buffer pipeline: __syncthreads (vmcnt drain) + stage-next overlap.
// ---------------------------------------------------------------------------
template <int BM, int BN, int ACT>
__device__ __forceinline__ void gemm_body(const u16* __restrict__ A,
                                          const u16* __restrict__ W,
                                          const float* __restrict__ bias,
                                          float* __restrict__ C32,
                                          u16* __restrict__ Cb,
                                          int K, int Mo,
                                          size_t row0, size_t col0) {
  constexpr int WM = BM / 2, WN = BN / 2, FM = WM / 16, FN = WN / 16;
  __shared__ __attribute__((aligned(16))) u16 As[2][BM * 64];
  __shared__ __attribute__((aligned(16))) u16 Bs[2][BN * 64];
  const int tid = threadIdx.x;
  const int w = tid >> 6, l = tid & 63, l15 = l & 15, l4 = l >> 4;
  const int lr = l >> 3, lc = l & 7;
  const int wr = (w >> 1) * WM, wc = (w & 1) * WN;
  const u16* Ab = A + row0 * K;
  const u16* Wb = W + col0 * K;
  f32x4 acc[FM][FN] = {};

  auto stage = [&](int buf, int k0) {
#pragma unroll
    for (int i = 0; i < BM / 32; ++i) {
      int sw = lr ^ ((i * 4 + w) & 7);
      int row = i * 32 + w * 8 + lr;
      const u16* ga = Ab + (size_t)row * K + k0 + ((lc ^ sw) & 7) * 8;
      __builtin_amdgcn_global_load_lds((const __attribute__((address_space(1))) void*)ga,
          (__attribute__((address_space(3))) void*)((char*)As[buf] + (i * 32 + w * 8) * 128), 16, 0, 0);
    }
#pragma unroll
    for (int i = 0; i < BN / 32; ++i) {
      int sw = lr ^ ((i * 4 + w) & 7);
      int row = i * 32 + w * 8 + lr;
      const u16* gw = Wb + (size_t)row * K + k0 + ((lc ^ sw) & 7) * 8;
      __builtin_amdgcn_global_load_lds((const __attribute__((address_space(1))) void*)gw,
          (__attribute__((address_space(3))) void*)((char*)Bs[buf] + (i * 32 + w * 8) * 128), 16, 0, 0);
    }
  };
  auto compute = [&](int buf) {
    const u16* AsC = As[buf];
    const u16* BsC = Bs[buf];
#pragma unroll
    for (int ks = 0; ks < 2; ++ks) {
      bf16x8 af[FM], bfr[FN];
#pragma unroll
      for (int m = 0; m < FM; ++m) {
        int ra = wr + m * 16 + l15;
        int sw = (l15 & 7) ^ ((wr / 8 + 2 * m + (l15 >> 3)) & 7);
        af[m] = *(const bf16x8*)&AsC[ra * 64 + ((ks * 32 + l4 * 8) ^ (sw * 8))];
      }
#pragma unroll
      for (int n = 0; n < FN; ++n) {
        int rb = wc + n * 16 + l15;
        int sw = (l15 & 7) ^ ((wc / 8 + 2 * n + (l15 >> 3)) & 7);
        bfr[n] = *(const bf16x8*)&BsC[rb * 64 + ((ks * 32 + l4 * 8) ^ (sw * 8))];
      }
#pragma unroll
      for (int m = 0; m < FM; ++m)
#pragma unroll
        for (int n = 0; n < FN; ++n)
          acc[m][n] = mfma16(af[m], bfr[n], acc[m][n]);
    }
  };

  const int nk = K / 64;
  stage(0, 0);
  int cur = 0;
  for (int kt = 0; kt < nk; ++kt) {
    __syncthreads();                 // drains vmcnt: stage(cur) landed
    if (kt + 1 < nk) stage(cur ^ 1, (kt + 1) * 64);   // overlap w/ compute
    compute(cur);
    cur ^= 1;
  }

#pragma unroll
  for (int n = 0; n < FN; ++n) {
    size_t col = col0 + wc + n * 16 + l15;
    float bv = bias[col];
#pragma unroll
    for (int m = 0; m < FM; ++m)
#pragma unroll
      for (int r = 0; r < 4; ++r) {
        size_t row = row0 + wr + m * 16 + l4 * 4 + r;
        float v = acc[m][n][r] + bv;
        if (ACT) v = 0.5f * v * (1.f + erff(v * 0.70710678118654752f));
        if (C32) C32[row * Mo + col] = v;
        if (Cb) Cb[row * Mo + col] = f2b(v);
      }
  }
}

// XS=1: bijective XCD column-chunk swizzle (requires gridDim.x % 8 == 0).
template <int BM, int BN, int ACT, int XS>
__global__ __launch_bounds__(256) void k_gemm_bf(const u16* __restrict__ A,
                                                 const u16* __restrict__ W,
                                                 const float* __restrict__ bias,
                                                 float* __restrict__ C32,
                                                 u16* __restrict__ Cb,
                                                 int K, int Mo) {
  int bx, by;
  if constexpr (XS) {
    int gx = gridDim.x;
    int bid = blockIdx.x + gx * blockIdx.y;
    int cw = gx >> 3;
    int xcd = bid & 7, j = bid >> 3;
    bx = xcd * cw + (j % cw);
    by = j / cw;
  } else {
    bx = blockIdx.x; by = blockIdx.y;
  }
  gemm_body<BM, BN, ACT>(A, W, bias, C32, Cb, K, Mo, (size_t)by * BM, (size_t)bx * BN);
}

// Merged cross-attention projections: job0 = q (4096x512), job1 = kv (2048x1024).
__global__ __launch_bounds__(256) void k_gemm_cross(
    const u16* __restrict__ A0, const u16* __restrict__ W0, const float* __restrict__ b0,
    u16* __restrict__ Co0,
    const u16* __restrict__ A1, const u16* __restrict__ W1, const float* __restrict__ b1,
    u16* __restrict__ Co1) {
  int bid = blockIdx.x;
  if (bid < 512) {                       // q: 64 row-tiles x 8 col-tiles
    int xcd = bid & 7, j = bid >> 3;
    gemm_body<64, 64, 0>(A0, W0, b0, nullptr, Co0, Ec, Ec, (size_t)j * 64, (size_t)xcd * 64);
  } else {                               // kv: 32 row-tiles x 16 col-tiles
    int r = bid - 512;
    int xcd = r & 7, j = r >> 3;
    int bx = xcd * 2 + (j & 1), by = j >> 1;
    gemm_body<64, 64, 0>(A1, W1, b1, nullptr, Co1, Ec, 2 * Ec, (size_t)by * 64, (size_t)bx * 64);
  }
}

// ---------------------------------------------------------------------------
// Flash attention fd2 + swapped QK^T (R8-proven, best-measured schedule).
// ---------------------------------------------------------------------------
__global__ __launch_bounds__(512, 4) void k_flash(const u16* __restrict__ Qp, int sq,
                                                  const u16* __restrict__ Kp,
                                                  const u16* __restrict__ Vp, int skv,
                                                  u16* __restrict__ Op, int so,
                                                  int Sq, int Sk, int causal) {
  __shared__ __attribute__((aligned(16))) u16 Kst[4][64 * 64];
  __shared__ __attribute__((aligned(16))) u16 Vt[4][64 * 64];
  __shared__ __attribute__((aligned(16))) u16 Pl[8][16 * 64];
  const int tid = threadIdx.x;
  const int w = tid >> 6, l = tid & 63, l15 = l & 15, l4 = l >> 4;
  const int wq = w & 3, ws = w >> 2;
  const int lr = l >> 3, lc = l & 7;
  const int t256 = tid & 255;
  const int kk2 = t256 >> 3, dblk = tid & 7;
  const int nqt = Sq / 64, nkt = Sk / 64;
  const int h = blockIdx.y, b = blockIdx.z;
  const int bx = blockIdx.x;
  const int qi = causal ? ((b & 1) ? bx : (nqt - 1 - bx)) : bx;
  const int qt0 = qi * 64;
  const int nt = causal ? (qi + 1) : nkt;
  const int NI = (nt + 1) >> 1;
  const u16* Qb = Qp + (size_t)b * Sq * sq + h * DH;
  const u16* Kb = Kp + (size_t)b * Sk * skv + h * DH;
  const u16* Vb = Vp + (size_t)b * Sk * skv + h * DH;
  const int qg = qt0 + wq * 16 + l15;

  bf16x8 qf[2];
  {
    const u16* qp0 = Qb + (size_t)qg * sq + l4 * 8;
    qf[0] = *(const bf16x8*)(qp0);
    qf[1] = *(const bf16x8*)(qp0 + 32);
  }

  f32x4 oacc[4] = {};
  float ls = 0.f, Mx = -3e38f;
  const float CSC = 0.18033688011112042f;
  const int swp = (l15 & 7) ^ (l15 >> 3);

  u16x8 va, vbv;
  auto stageK = [&](int slot, int kt) {
#pragma unroll
    for (int i = 0; i < 2; ++i) {
      int sw = lr ^ ((i * 4 + wq) & 7);
      int row = i * 32 + wq * 8 + lr;
      const u16* src = Kb + (size_t)(kt + row) * skv + ((lc ^ sw) & 7) * 8;
      __builtin_amdgcn_global_load_lds((const __attribute__((address_space(1))) void*)src,
          (__attribute__((address_space(3))) void*)((char*)Kst[slot] + (i * 32 + wq * 8) * 128), 16, 0, 0);
    }
  };
  auto loadV = [&](int kt) {
    const u16* vp0 = Vb + (size_t)(kt + 2 * kk2) * skv + dblk * 8;
    va = *(const u16x8*)vp0;
    vbv = *(const u16x8*)(vp0 + skv);
  };
  auto writeV = [&](int slot) {
    char* Vb_ = (char*)Vt[slot];
#pragma unroll
    for (int j = 0; j < 8; ++j) {
      int d = dblk * 8 + j;
      int sw = (j ^ dblk) & 7;
      unsigned pk = (unsigned)va[j] | ((unsigned)vbv[j] << 16);
      *(unsigned*)(Vb_ + d * 128 + ((4 * kk2) ^ (sw << 4))) = pk;
    }
  };

  stageK(ws * 2, ws * 64);
  loadV(ws * 64);
  writeV(ws * 2);
  asm volatile("s_waitcnt lgkmcnt(0)" ::: "memory");
  __builtin_amdgcn_sched_barrier(0);
  __builtin_amdgcn_s_barrier();

  u16* Pw = Pl[w];
  for (int i = 0; i < NI; ++i) {
    const int t = 2 * i + ws;
    const int tn = t + 2;
    const int cur = ws * 2 + (i & 1);
    const int nxt = ws * 2 + ((i + 1) & 1);
    const bool haveNext = tn < nt;
    if (haveNext) {
      stageK(nxt, tn * 64);
      loadV(tn * 64);
    }
    if (t < nt) {
      const u16* KstC = Kst[cur];
      const u16* VtC = Vt[cur];

      f32x4 sf[4] = {};
      __builtin_amdgcn_s_setprio(1);
#pragma unroll
      for (int n = 0; n < 4; ++n) {
        int rk = n * 16 + l15;
        int sw = (l15 & 7) ^ ((2 * n + (l15 >> 3)) & 7);
#pragma unroll
        for (int ks = 0; ks < 2; ++ks) {
          bf16x8 kf = *(const bf16x8*)&KstC[rk * 64 + ((ks * 32 + l4 * 8) ^ (sw * 8))];
          sf[n] = mfma16(kf, qf[ks], sf[n]);
        }
      }
      __builtin_amdgcn_s_setprio(0);

      if (causal && t == nt - 1) {
#pragma unroll
        for (int n = 0; n < 4; ++n)
#pragma unroll
          for (int r = 0; r < 4; ++r) {
            int kcol = t * 64 + n * 16 + l4 * 4 + r;
            if (kcol > qg) sf[n][r] = -3e38f;
          }
      }

      float tm = fmaxf(fmaxf(fmaxf(sf[0][0], sf[0][1]), fmaxf(sf[0][2], sf[0][3])),
                       fmaxf(fmaxf(sf[1][0], sf[1][1]), fmaxf(sf[1][2], sf[1][3])));
      tm = fmaxf(tm, fmaxf(fmaxf(fmaxf(sf[2][0], sf[2][1]), fmaxf(sf[2][2], sf[2][3])),
                           fmaxf(fmaxf(sf[3][0], sf[3][1]), fmaxf(sf[3][2], sf[3][3]))));
      tm = fmaxf(tm, __shfl_xor(tm, 16, 64));
      tm = fmaxf(tm, __shfl_xor(tm, 32, 64));
      float Mn = fmaxf(Mx, tm);
      float al = exp2f((Mx - Mn) * CSC);
      Mx = Mn;
      float mxc = Mx * CSC;

      float rs = 0.f;
#pragma unroll
      for (int n = 0; n < 4; ++n) {
        float p0 = exp2f(sf[n][0] * CSC - mxc);
        float p1 = exp2f(sf[n][1] * CSC - mxc);
        float p2 = exp2f(sf[n][2] * CSC - mxc);
        float p3 = exp2f(sf[n][3] * CSC - mxc);
        rs += (p0 + p1) + (p2 + p3);
        unsigned w0 = (unsigned)f2b(p0) | ((unsigned)f2b(p1) << 16);
        unsigned w1 = (unsigned)f2b(p2) | ((unsigned)f2b(p3) << 16);
        int bb = (n * 32 + l4 * 8) ^ (swp << 4);
        *(unsigned*)((char*)Pw + l15 * 128 + bb) = w0;
        *(unsigned*)((char*)Pw + l15 * 128 + bb + 4) = w1;
      }
      rs += __shfl_xor(rs, 16, 64);
      rs += __shfl_xor(rs, 32, 64);
      ls = ls * al + rs;

      if (__any(al < 1.f)) {
        float a0 = __shfl(al, l4 * 4 + 0, 64);
        float a1 = __shfl(al, l4 * 4 + 1, 64);
        float a2 = __shfl(al, l4 * 4 + 2, 64);
        float a3 = __shfl(al, l4 * 4 + 3, 64);
#pragma unroll
        for (int n2 = 0; n2 < 4; ++n2) {
          oacc[n2][0] *= a0; oacc[n2][1] *= a1;
          oacc[n2][2] *= a2; oacc[n2][3] *= a3;
        }
      }

      asm volatile("s_waitcnt lgkmcnt(0)" ::: "memory");
      __builtin_amdgcn_sched_barrier(0);

      __builtin_amdgcn_s_setprio(1);
#pragma unroll
      for (int ks = 0; ks < 2; ++ks) {
        bf16x8 pf = *(const bf16x8*)((char*)Pw + l15 * 128 + ((ks * 64 + l4 * 16) ^ (swp << 4)));
#pragma unroll
        for (int n2 = 0; n2 < 4; ++n2) {
          int rd = n2 * 16 + l15;
          int sw = (l15 & 7) ^ ((2 * n2 + (l15 >> 3)) & 7);
          bf16x8 vf = *(const bf16x8*)((char*)VtC + rd * 128 + ((ks * 64 + l4 * 16) ^ (sw << 4)));
          oacc[n2] = mfma16(pf, vf, oacc[n2]);
        }
      }
      __builtin_amdgcn_s_setprio(0);
    }

    if (haveNext) writeV(nxt);
    asm volatile("s_waitcnt lgkmcnt(0)" ::: "memory");
    __builtin_amdgcn_sched_barrier(0);
    __builtin_amdgcn_s_barrier();
  }

  __syncthreads();
  float* OB = (float*)&Kst[0][0];
  float* ML = (float*)&Vt[0][0];
  if (l4 == 0) {
    ML[ws * 64 + wq * 16 + l15] = Mx;
    ML[128 + ws * 64 + wq * 16 + l15] = ls;
  }
  if (ws == 1) {
#pragma unroll
    for (int n2 = 0; n2 < 4; ++n2)
#pragma unroll
      for (int r = 0; r < 4; ++r)
        OB[(wq * 16 + l4 * 4 + r) * 64 + n2 * 16 + l15] = oacc[n2][r];
  }
  __syncthreads();
  if (ws == 0) {
    u16* Ob = Op + (size_t)b * Sq * so + h * DH;
#pragma unroll
    for (int r = 0; r < 4; ++r) {
      int qs = wq * 16 + l4 * 4 + r;
      float mA = ML[qs], mB = ML[64 + qs];
      float lA = ML[128 + qs], lB = ML[192 + qs];
      float M = fmaxf(mA, mB);
      float aA = exp2f((mA - M) * CSC);
      float aB = exp2f((mB - M) * CSC);
      float inv = 1.f / (lA * aA + lB * aB);
      int qrow = qt0 + qs;
#pragma unroll
      for (int n2 = 0; n2 < 4; ++n2) {
        float o = (oacc[n2][r] * aA + OB[qs * 64 + n2 * 16 + l15] * aB) * inv;
        Ob[(size_t)qrow * so + n2 * 16 + l15] = f2b(o);
      }
    }
  }
}

// ---------------------------------------------------------------------------
// Residual + LayerNorm: one WAVE per row, 4 rows/block; thread l owns
// contiguous elements 8l..8l+7. Residual branch input is bf16 (rres).
// outf may be null (final LN).
// ---------------------------------------------------------------------------
__global__ __launch_bounds__(256) void k_res_ln(const float* __restrict__ xin,
                                                const u16* __restrict__ rres,
                                                const float* __restrict__ g,
                                                const float* __restrict__ bet,
                                                float* __restrict__ outf,
                                                u16* __restrict__ outb,
                                                int has_res) {
  const int tid = threadIdx.x, w = tid >> 6, l = tid & 63;
  const int row = blockIdx.x * 4 + w;
  const float4* xr = (const float4*)(xin + (size_t)row * Ec);
  float4 a = xr[2 * l], c = xr[2 * l + 1];
  if (has_res) {
    uint4 rv = ((const uint4*)(rres + (size_t)row * Ec))[l];  // elems 8l..8l+7
    a.x += b2f_lo(rv.x); a.y += b2f_hi(rv.x);
    a.z += b2f_lo(rv.y); a.w += b2f_hi(rv.y);
    c.x += b2f_lo(rv.z); c.y += b2f_hi(rv.z);
    c.z += b2f_lo(rv.w); c.w += b2f_hi(rv.w);
  }
  float s = (a.x + a.y) + (a.z + a.w) + (c.x + c.y) + (c.z + c.w);
#pragma unroll
  for (int o = 32; o; o >>= 1) s += __shfl_xor(s, o, 64);
  const float mean = s * (1.f / Ec);
  float d0 = a.x - mean, d1 = a.y - mean, d2 = a.z - mean, d3 = a.w - mean;
  float e0 = c.x - mean, e1 = c.y - mean, e2 = c.z - mean, e3 = c.w - mean;
  float vs = d0 * d0 + d1 * d1 + d2 * d2 + d3 * d3 +
             e0 * e0 + e1 * e1 + e2 * e2 + e3 * e3;
#pragma unroll
  for (int o = 32; o; o >>= 1) vs += __shfl_xor(vs, o, 64);
  const float inv = rsqrtf(vs * (1.f / Ec) + 1e-5f);
  float4 g0 = ((const float4*)g)[2 * l], g1 = ((const float4*)g)[2 * l + 1];
  float4 b0 = ((const float4*)bet)[2 * l], b1 = ((const float4*)bet)[2 * l + 1];
  float o0 = d0 * inv * g0.x + b0.x, o1 = d1 * inv * g0.y + b0.y;
  float o2 = d2 * inv * g0.z + b0.z, o3 = d3 * inv * g0.w + b0.w;
  float o4 = e0 * inv * g1.x + b1.x, o5 = e1 * inv * g1.y + b1.y;
  float o6 = e2 * inv * g1.z + b1.z, o7 = e3 * inv * g1.w + b1.w;
  if (outf) {
    float4* orow = (float4*)(outf + (size_t)row * Ec);
    orow[2 * l] = make_float4(o0, o1, o2, o3);
    orow[2 * l + 1] = make_float4(o4, o5, o6, o7);
  }
  if (outb) {
    uint4 pk;
    pk.x = (unsigned)f2b(o0) | ((unsigned)f2b(o1) << 16);
    pk.y = (unsigned)f2b(o2) | ((unsigned)f2b(o3) << 16);
    pk.z = (unsigned)f2b(o4) | ((unsigned)f2b(o5) << 16);
    pk.w = (unsigned)f2b(o6) | ((unsigned)f2b(o7) << 16);
    ((uint4*)(outb + (size_t)row * Ec))[l] = pk;
  }
}

// ---------------------------------------------------------------------------
extern "C" void kernel_launch(void* const* d_in, const int* in_sizes, int n_in,
                              void* d_out, int out_size, void* d_ws, size_t ws_size,
                              hipStream_t stream) {
  const float* encoded      = (const float*)d_in[0];
  const int*   seq          = (const int*)d_in[1];
  const float* input_embed  = (const float*)d_in[2];
  const float* pos_embed    = (const float*)d_in[3];
  const float* output_bias  = (const float*)d_in[4];
  const float* self_in_w    = (const float*)d_in[5];
  const float* self_in_b    = (const float*)d_in[6];
  const float* self_out_w   = (const float*)d_in[7];
  const float* self_out_b   = (const float*)d_in[8];
  const float* cross_in_w   = (const float*)d_in[9];
  const float* cross_in_b   = (const float*)d_in[10];
  const float* cross_out_w  = (const float*)d_in[11];
  const float* cross_out_b  = (const float*)d_in[12];
  const float* self_norm_g  = (const float*)d_in[13];
  const float* self_norm_b  = (const float*)d_in[14];
  const float* cross_norm_g = (const float*)d_in[15];
  const float* cross_norm_b = (const float*)d_in[16];
  const float* mlp_norm_g   = (const float*)d_in[17];
  const float* mlp_norm_b   = (const float*)d_in[18];
  const float* lin1_w       = (const float*)d_in[19];
  const float* lin1_b       = (const float*)d_in[20];
  const float* lin2_w       = (const float*)d_in[21];
  const float* lin2_b       = (const float*)d_in[22];
  const float* final_norm_g = (const float*)d_in[23];
  const float* final_norm_b = (const float*)d_in[24];

  char* oc = (char*)d_out;
  auto take = [&](size_t bytes) { char* p = oc; oc += bytes; return p; };
  u16* wsi  = (u16*)take((size_t)Lc * 3 * Ec * Ec * 2);
  u16* wso  = (u16*)take((size_t)Lc * Ec * Ec * 2);
  u16* wci  = (u16*)take((size_t)Lc * 3 * Ec * Ec * 2);
  u16* wco  = (u16*)take((size_t)Lc * Ec * Ec * 2);
  u16* wl1  = (u16*)take((size_t)Lc * Fc * Ec * 2);
  u16* wl2  = (u16*)take((size_t)Lc * Ec * Fc * 2);
  u16* encb = (u16*)take((size_t)NMc * Ec * 2);
  float* xs  = (float*)take((size_t)Nc * Ec * 4);
  float* ys  = (float*)take((size_t)Nc * Ec * 4);
  u16* tmpb = (u16*)take((size_t)Nc * Ec * 2);
  u16* xbf  = (u16*)take((size_t)Nc * Ec * 2);
  u16* qkvb = (u16*)take((size_t)Nc * 3 * Ec * 2);
  u16* ctxb = (u16*)take((size_t)Nc * Ec * 2);
  u16* qxb  = (u16*)take((size_t)Nc * Ec * 2);
  u16* kvb  = (u16*)take((size_t)NMc * 2 * Ec * 2);
  u16* hbf  = (u16*)take((size_t)Nc * Fc * 2);
  u16* xfb  = (u16*)d_ws;
  u16* embb = (u16*)((char*)d_ws + (size_t)Nc * Ec * 2);

  const dim3 blk(256);
  k_cvt_all<<<dim3(C8 / 256), blk, 0, stream>>>(
      self_in_w, self_out_w, cross_in_w, cross_out_w, lin1_w, lin2_w,
      input_embed, encoded, wsi, wso, wci, wco, wl1, wl2, embb, encb,
      seq, pos_embed, xs, xbf);

  const dim3 gAttn(Sc / 64, Hc, Bc);
  const dim3 blkA(512);
  const dim3 gLN(Nc / 4);
  for (int l = 0; l < Lc; ++l) {
    const u16* wsi_l = wsi + (size_t)l * 3 * Ec * Ec;
    const u16* wci_l = wci + (size_t)l * 3 * Ec * Ec;
    // self attention
    k_gemm_bf<128, 64, 0, 1><<<dim3(3 * Ec / 64, Nc / 128), blk, 0, stream>>>(
        xbf, wsi_l, self_in_b + (size_t)l * 3 * Ec, nullptr, qkvb, Ec, 3 * Ec);
    k_flash<<<gAttn, blkA, 0, stream>>>(qkvb, 3 * Ec, qkvb + Ec, qkvb + 2 * Ec, 3 * Ec,
                                        ctxb, Ec, Sc, Sc, 1);
    k_gemm_bf<64, 64, 0, 1><<<dim3(Ec / 64, Nc / 64), blk, 0, stream>>>(
        ctxb, wso + (size_t)l * Ec * Ec, self_out_b + (size_t)l * Ec, nullptr, tmpb, Ec, Ec);
    k_res_ln<<<gLN, blk, 0, stream>>>(xs, tmpb, self_norm_g + (size_t)l * Ec,
                                      self_norm_b + (size_t)l * Ec, ys, xbf, 1);
    // cross attention: q + kv projections merged in one dispatch
    k_gemm_cross<<<dim3(1024), blk, 0, stream>>>(
        xbf, wci_l, cross_in_b + (size_t)l * 3 * Ec, qxb,
        encb, wci_l + (size_t)Ec * Ec, cross_in_b + (size_t)l * 3 * Ec + Ec, kvb);
    k_flash<<<gAttn, blkA, 0, stream>>>(qxb, Ec, kvb, kvb + Ec, 2 * Ec,
                                        ctxb, Ec, Sc, Mc, 0);
    k_gemm_bf<64, 64, 0, 1><<<dim3(Ec / 64, Nc / 64), blk, 0, stream>>>(
        ctxb, wco + (size_t)l * Ec * Ec, cross_out_b + (size_t)l * Ec, nullptr, tmpb, Ec, Ec);
    k_res_ln<<<gLN, blk, 0, stream>>>(ys, tmpb, cross_norm_g + (size_t)l * Ec,
                                      cross_norm_b + (size_t)l * Ec, xs, xbf, 1);
    // MLP
    k_gemm_bf<128, 128, 1, 1><<<dim3(Fc / 128, Nc / 128), blk, 0, stream>>>(
        xbf, wl1 + (size_t)l * Fc * Ec, lin1_b + (size_t)l * Fc, nullptr, hbf, Ec, Fc);
    k_gemm_bf<64, 64, 0, 1><<<dim3(Ec / 64, Nc / 64), blk, 0, stream>>>(
        hbf, wl2 + (size_t)l * Ec * Fc, lin2_b + (size_t)l * Ec, nullptr, tmpb, Fc, Ec);
    k_res_ln<<<gLN, blk, 0, stream>>>(xs, tmpb, mlp_norm_g + (size_t)l * Ec,
                                      mlp_norm_b + (size_t)l * Ec, xs, xbf, 1);
  }

  k_res_ln<<<gLN, blk, 0, stream>>>(xs, nullptr, final_norm_g, final_norm_b, nullptr, xfb, 0);
  k_gemm_bf<128, 128, 0, 1><<<dim3(Vc / 128, Nc / 128), blk, 0, stream>>>(
      xfb, embb, output_bias, (float*)d_out, nullptr, Ec, Vc);
}